// Round 6
// baseline (722.698 us; speedup 1.0000x reference)
//
#include <hip/hip_runtime.h>

// ---------------------------------------------------------------------------
// PositionEncoder: per token (B*T = 262144), output 272 f32:
//   x[0:6] | emb[idx1] (128) | x[6:10] | emb[idx2] (128) | x[10:16]
//
// R10 = SLEEP PROBE (intentionally ~220us slower; R8 + s_sleep tail).
//  Goal: surface OUR kernel in the top-5 counter table for the first time.
//  R9 (double-store) failed: +27us only, fills (~198us) still covered us.
//  The +27us DID prove store issue + L2 write path for a full extra pass is
//  cheap => R8's 115us residual is not issue-bound. Remaining question:
//  does the plain-store stream RFO-fetch its output lines from HBM?
//  s_sleep adds ZERO memory/VALU ops => FETCH_SIZE / WRITE_SIZE in the
//  counter row are exactly the real R8 stream's:
//    FETCH >= 250 MB => RFO real => floor ~93us, R8(115us)~81% => roofline.
//    FETCH <= 40 MB  => no RFO => real floor ~50us => attack issue/latency.
// ---------------------------------------------------------------------------

#define TOK 64          // tokens per block
#define THREADS 256

typedef float vfloat4 __attribute__((ext_vector_type(4)));  // native vector

constexpr float kNX[26] = {
    0.5454545454545454f, 0.6022727272727273f, 0.5454545454545454f,
    0.6022727272727273f, 0.4772727272727273f, 0.42045454545454547f,
    0.42045454545454547f, 0.4772727272727273f, 0.32954545454545453f,
    0.42045454545454547f, 0.4772727272727273f, 0.4772727272727273f,
    0.42045454545454547f, 0.32954545454545453f, 0.5727272727272728f,
    0.7613636363636364f, 0.8181818181818182f, 0.8181818181818182f,
    0.7613636363636364f, 0.7909090909090909f, 0.9431818181818182f,
    1.0f, 1.0f, 0.9431818181818182f, 0.9727272727272728f, 0.9727272727272728f};
constexpr float kNY[26] = {
    0.76f, 0.76f, 0.86f, 0.86f, 0.76f, 0.76f, 0.86f, 0.86f, 0.808f,
    0.48f, 0.48f, 0.38f, 0.38f, 0.428f, 0.62f, 0.76f, 0.76f, 0.86f,
    0.86f, 0.62f, 0.76f, 0.76f, 0.86f, 0.86f, 0.62f, 1.0f};

__device__ __forceinline__ int point_index(float px, float py) {
#pragma clang fp contract(off)
    int idx = 0;
#pragma unroll
    for (int n = 25; n >= 0; --n) {
        float tx = 0.01f + 1.0e-5f * kNX[n];
        float ty = 0.01f + 1.0e-5f * kNY[n];
        bool c = (fabsf(px - kNX[n]) <= tx) && (fabsf(py - kNY[n]) <= ty);
        if (c) idx = n + 1;
    }
    return idx;
}

__global__ __launch_bounds__(THREADS) void pos_enc_kernel(
    const float* __restrict__ x, const float* __restrict__ emb,
    float* __restrict__ out, int n_tokens) {
    __shared__ float xs[TOK * 16];      // 4 KB   staged x tile
    __shared__ float semb[27 * 128];    // 13.5 KB emb rows 0..26 (reachable set)
    __shared__ int   sidx[2 * TOK];     // 0.5 KB node indices

    const int tid  = threadIdx.x;
    const int tok0 = blockIdx.x * TOK;
    const int ntok = min(TOK, n_tokens - tok0);

    // ---- stage emb rows 0..26: 864 float4, coalesced, L2-hot after block 0
    for (int i = tid; i < 27 * 32; i += THREADS)
        ((vfloat4*)semb)[i] = ((const vfloat4*)emb)[i];

    // ---- stage x tile (1 float4/thread) + node indices from the staging reg
    if (tid < ntok * 4) {
        vfloat4 v = ((const vfloat4*)x)[(long long)tok0 * 4 + tid];
        ((vfloat4*)xs)[tid] = v;
        int q = tid & 3, t = tid >> 2;
        if (q == 1) sidx[t]       = point_index(v.x, v.y);
        if (q == 2) sidx[TOK + t] = point_index(v.x, v.y);
    }
    __syncthreads();   // the only barrier

    // Half h (float2 units, 0..135):
    //   h<3: x[2h..]  h<67: e1[2h-6..]  h<69: x[2h-128..]
    //   h<133: e2[2h-138..]  else x[2h-256..]     (verified: absmax 0)
    const float2* xs2 = (const float2*)xs;
    const float2* se2 = (const float2*)semb;
    const long long out4 = (long long)tok0 * 68;

    // exact for l < ~1M: floor(l*61681 / 2^22) == floor(l/68)
#define BODY(lv)                                                           \
    {                                                                      \
        const int l_ = (lv);                                               \
        int t  = (int)(((unsigned)l_ * 61681u) >> 22);                     \
        int j  = l_ - t * 68;                                              \
        int i1 = sidx[t];                                                  \
        int i2 = sidx[TOK + t];                                            \
        int tb = t * 8;                                                    \
        int h0 = 2 * j;                                                    \
        const float2* p0 = (h0 < 3)   ? xs2 + tb + h0                      \
                         : (h0 < 67)  ? se2 + i1 * 64 + (h0 - 3)           \
                         : (h0 < 69)  ? xs2 + tb + (h0 - 64)               \
                         : (h0 < 133) ? se2 + i2 * 64 + (h0 - 69)          \
                         :              xs2 + tb + (h0 - 128);             \
        int h1 = h0 + 1;                                                   \
        const float2* p1 = (h1 < 3)   ? xs2 + tb + h1                      \
                         : (h1 < 67)  ? se2 + i1 * 64 + (h1 - 3)           \
                         : (h1 < 69)  ? xs2 + tb + (h1 - 64)               \
                         : (h1 < 133) ? se2 + i2 * 64 + (h1 - 69)          \
                         :              xs2 + tb + (h1 - 128);             \
        float2 a = *p0, b = *p1;                                           \
        vfloat4 v; v.x = a.x; v.y = a.y; v.z = b.x; v.w = b.y;             \
        ((vfloat4*)out)[out4 + l_] = v;   /* plain store */                \
    }

    if (ntok == TOK) {
        // full block: every thread does exactly 17 vec4 (64*68/256)
#pragma unroll 4
        for (int k = 0; k < 17; ++k) BODY(tid + (k << 8));
    } else {
        const int nvec = ntok * 68;
        for (int l = tid; l < nvec; l += THREADS) BODY(l);
    }
#undef BODY

    // ---- PROBE TAIL: ~524K cycles of s_sleep (~220us @2.4GHz) per wave.
    // No memory ops, no VALU: FETCH/WRITE counters = the real stream above.
    // Store drain overlaps the sleep; removed entirely in R11.
#pragma unroll 1
    for (int i = 0; i < 1024; ++i)
        asm volatile("s_sleep 8");
}

extern "C" void kernel_launch(void* const* d_in, const int* in_sizes, int n_in,
                              void* d_out, int out_size, void* d_ws, size_t ws_size,
                              hipStream_t stream) {
    const float* x   = (const float*)d_in[0];   // [B, T, 16] f32
    const float* emb = (const float*)d_in[1];   // [100, 128] f32
    float* out = (float*)d_out;                 // [B, T, 272] f32

    int n_tokens = in_sizes[0] / 16;            // 262144
    int nblocks  = (n_tokens + TOK - 1) / TOK;  // 4096

    pos_enc_kernel<<<nblocks, THREADS, 0, stream>>>(x, emb, out, n_tokens);
}

// Round 7
// 314.523 us; speedup vs baseline: 2.2978x; 2.2978x over previous
//
#include <hip/hip_runtime.h>

// ---------------------------------------------------------------------------
// PositionEncoder: per token (B*T = 262144), output 272 f32:
//   x[0:6] | emb[idx1] (128) | x[6:10] | emb[idx2] (128) | x[10:16]
//
// Counter evidence through R10 (sleep probe; first direct read):
//   FETCH=8.3MB (NO write-allocate/RFO), WRITE=278.5MB (=output exactly),
//   bank-conflict ~2us, VGPR_Count=12. Traffic floor ~47us; R8 ran ~115us
//   at ~2.5TB/s effective while the harness fill (same store instr, same
//   buffer) hits 6.3TB/s at 9.7% occupancy. R9: a full 2nd store pass cost
//   only +27us => issue is cheap. Diagnosis: with 12 VGPR each store waits
//   on its own ds_read pair (~1 outstanding store/wave); the fill has
//   dozens outstanding. Store-QUEUE DEPTH is the untested lever.
// R11: fill-mimic. Per tile: compute all 17 vec4 into vv[17] registers
//   (full unroll), sched_barrier(0), then 17 back-to-back dwordx4 stores.
//   4 tiles/block with per-tile LDS buffers => ONE barrier per kernel, no
//   vmcnt(0) drains between tiles, emb staged once per 256 tokens.
// ---------------------------------------------------------------------------

#define TOK 64          // tokens per tile
#define TPB 4           // tiles per block
#define THREADS 256

typedef float vfloat4 __attribute__((ext_vector_type(4)));  // native vector

constexpr float kNX[26] = {
    0.5454545454545454f, 0.6022727272727273f, 0.5454545454545454f,
    0.6022727272727273f, 0.4772727272727273f, 0.42045454545454547f,
    0.42045454545454547f, 0.4772727272727273f, 0.32954545454545453f,
    0.42045454545454547f, 0.4772727272727273f, 0.4772727272727273f,
    0.42045454545454547f, 0.32954545454545453f, 0.5727272727272728f,
    0.7613636363636364f, 0.8181818181818182f, 0.8181818181818182f,
    0.7613636363636364f, 0.7909090909090909f, 0.9431818181818182f,
    1.0f, 1.0f, 0.9431818181818182f, 0.9727272727272728f, 0.9727272727272728f};
constexpr float kNY[26] = {
    0.76f, 0.76f, 0.86f, 0.86f, 0.76f, 0.76f, 0.86f, 0.86f, 0.808f,
    0.48f, 0.48f, 0.38f, 0.38f, 0.428f, 0.62f, 0.76f, 0.76f, 0.86f,
    0.86f, 0.62f, 0.76f, 0.76f, 0.86f, 0.86f, 0.62f, 1.0f};

__device__ __forceinline__ int point_index(float px, float py) {
#pragma clang fp contract(off)
    int idx = 0;
    // Reverse iterate + overwrite => lowest-index match wins (== argmax of
    // the boolean "close" vector, matching the reference exactly).
#pragma unroll
    for (int n = 25; n >= 0; --n) {
        float tx = 0.01f + 1.0e-5f * kNX[n];
        float ty = 0.01f + 1.0e-5f * kNY[n];
        bool c = (fabsf(px - kNX[n]) <= tx) && (fabsf(py - kNY[n]) <= ty);
        if (c) idx = n + 1;
    }
    return idx;
}

// Output vec4 #l_ of a 64-token tile (verified mapping, absmax 0 since R6).
// Half h (float2 units, 0..135):
//   h<3: x[2h..]  h<67: e1[2h-6..]  h<69: x[2h-128..]
//   h<133: e2[2h-138..]  else x[2h-256..]
__device__ __forceinline__ vfloat4 make_v(const float2* __restrict__ xs2,
                                          const float2* __restrict__ se2,
                                          const int* __restrict__ sx, int l_) {
    // exact for l_ < ~1M: floor(l_*61681 / 2^22) == floor(l_/68)
    int t  = (int)(((unsigned)l_ * 61681u) >> 22);
    int j  = l_ - t * 68;
    int i1 = sx[t];
    int i2 = sx[TOK + t];
    int tb = t * 8;
    int h0 = 2 * j, h1 = h0 + 1;
    const float2* p0 = (h0 < 3)   ? xs2 + tb + h0
                     : (h0 < 67)  ? se2 + i1 * 64 + (h0 - 3)
                     : (h0 < 69)  ? xs2 + tb + (h0 - 64)
                     : (h0 < 133) ? se2 + i2 * 64 + (h0 - 69)
                     :              xs2 + tb + (h0 - 128);
    const float2* p1 = (h1 < 3)   ? xs2 + tb + h1
                     : (h1 < 67)  ? se2 + i1 * 64 + (h1 - 3)
                     : (h1 < 69)  ? xs2 + tb + (h1 - 64)
                     : (h1 < 133) ? se2 + i2 * 64 + (h1 - 69)
                     :              xs2 + tb + (h1 - 128);
    float2 a = *p0, b = *p1;
    vfloat4 v; v.x = a.x; v.y = a.y; v.z = b.x; v.w = b.y;
    return v;
}

__global__ __launch_bounds__(THREADS) void pos_enc_kernel(
    const float* __restrict__ x, const float* __restrict__ emb,
    float* __restrict__ out, int n_tokens) {
    __shared__ float xs[TPB][TOK * 16];   // 16 KB  staged x, per tile
    __shared__ float semb[27 * 128];      // 13.5 KB emb rows 0..26 (reachable)
    __shared__ int   sidx[TPB][2 * TOK];  // 2 KB   node indices, per tile

    const int tid = threadIdx.x;
    const long long base_tok = (long long)blockIdx.x * (TPB * TOK);

    // ---- stage emb rows 0..26 once per block (864 float4, coalesced) ----
    for (int i = tid; i < 27 * 32; i += THREADS)
        ((vfloat4*)semb)[i] = ((const vfloat4*)emb)[i];

    // ---- stage all 4 tiles' x + node indices (4 coalesced float4/thread) --
#pragma unroll
    for (int tile = 0; tile < TPB; ++tile) {
        long long tok0 = base_tok + tile * TOK;
        if (tok0 >= n_tokens) break;
        int ntok = min(TOK, (int)(n_tokens - tok0));
        if (tid < ntok * 4) {
            vfloat4 v = ((const vfloat4*)x)[tok0 * 4 + tid];
            ((vfloat4*)&xs[tile][0])[tid] = v;
            int q = tid & 3, t = tid >> 2;
            if (q == 1) sidx[tile][t]       = point_index(v.x, v.y);
            if (q == 2) sidx[tile][TOK + t] = point_index(v.x, v.y);
        }
    }
    __syncthreads();   // the ONLY barrier: no store drains after this point

    const float2* se2 = (const float2*)semb;

    // ---- per tile: gather 17 vec4 into registers, then burst 17 stores ----
#pragma unroll 1
    for (int tile = 0; tile < TPB; ++tile) {
        long long tok0 = base_tok + tile * TOK;
        if (tok0 >= n_tokens) break;
        int ntok = min(TOK, (int)(n_tokens - tok0));
        const float2* xs2 = (const float2*)&xs[tile][0];
        const int*    sx  = &sidx[tile][0];
        const long long out4 = tok0 * 68;

        if (ntok == TOK) {
            vfloat4 vv[17];                       // 68 VGPR: buys store depth
#pragma unroll
            for (int k = 0; k < 17; ++k)
                vv[k] = make_v(xs2, se2, sx, tid + (k << 8));
            __builtin_amdgcn_sched_barrier(0);    // keep stores AFTER reads
#pragma unroll
            for (int k = 0; k < 17; ++k)
                ((vfloat4*)out)[out4 + tid + (k << 8)] = vv[k];
        } else {
            const int nvec = ntok * 68;
            for (int l = tid; l < nvec; l += THREADS)
                ((vfloat4*)out)[out4 + l] = make_v(xs2, se2, sx, l);
        }
    }
}

extern "C" void kernel_launch(void* const* d_in, const int* in_sizes, int n_in,
                              void* d_out, int out_size, void* d_ws, size_t ws_size,
                              hipStream_t stream) {
    const float* x   = (const float*)d_in[0];   // [B, T, 16] f32
    const float* emb = (const float*)d_in[1];   // [100, 128] f32
    float* out = (float*)d_out;                 // [B, T, 272] f32

    int n_tokens = in_sizes[0] / 16;                 // 262144
    int ntiles   = (n_tokens + TOK - 1) / TOK;       // 4096
    int nblocks  = (ntiles + TPB - 1) / TPB;         // 1024

    pos_enc_kernel<<<nblocks, THREADS, 0, stream>>>(x, emb, out, n_tokens);
}

// Round 8
// 305.834 us; speedup vs baseline: 2.3630x; 1.0284x over previous
//
#include <hip/hip_runtime.h>

// ---------------------------------------------------------------------------
// PositionEncoder: per token (B*T = 262144), output 272 f32:
//   x[0:6] | emb[idx1] (128) | x[6:10] | emb[idx2] (128) | x[10:16]
//
// Evidence ledger through R11:
//   R10 probe: FETCH=8.3MB (no RFO), WRITE=278.5MB (=output), VGPR=12.
//   R9: duplicate L2-warm store pass costs only +27us (issue+L2 path cheap).
//   R11: 17-deep prematerialized store bursts, 1 barrier, 4 tiles/block:
//        NULL (residual ~121us). Store flavor (R8), occupancy (R6), LDS
//        out-tile (R2/R4), template compute (R7): all null at 115-125us.
//   Fill writes same buffer, same instr, at 6.3TB/s; we sit at 2.5TB/s.
// R12: the one unvaried axis = store ADDRESS PATTERN. All prior kernels:
//   ~2048 concurrent per-block contiguous streams. The fill: ONE global
//   sliding window (grid-strided), dependency-free iterations. R12 clones
//   that: dispatch A precomputes idx pairs into d_ws (1MB, L2-hot);
//   dispatch B is a pure grid-strided writer (no LDS, no barriers,
//   independent iterations): per vec4, 1 ws dword + 2 float2 loads
//   (emb table L2-hot; x slides with the window) + 1 plain dwordx4 store.
//   Fallback to R8 kernel if ws_size < n_tokens*4.
// ---------------------------------------------------------------------------

#define THREADS 256
#define TOK 64          // fallback kernel tile

typedef float vfloat4 __attribute__((ext_vector_type(4)));  // native vector

constexpr float kNX[26] = {
    0.5454545454545454f, 0.6022727272727273f, 0.5454545454545454f,
    0.6022727272727273f, 0.4772727272727273f, 0.42045454545454547f,
    0.42045454545454547f, 0.4772727272727273f, 0.32954545454545453f,
    0.42045454545454547f, 0.4772727272727273f, 0.4772727272727273f,
    0.42045454545454547f, 0.32954545454545453f, 0.5727272727272728f,
    0.7613636363636364f, 0.8181818181818182f, 0.8181818181818182f,
    0.7613636363636364f, 0.7909090909090909f, 0.9431818181818182f,
    1.0f, 1.0f, 0.9431818181818182f, 0.9727272727272728f, 0.9727272727272728f};
constexpr float kNY[26] = {
    0.76f, 0.76f, 0.86f, 0.86f, 0.76f, 0.76f, 0.86f, 0.86f, 0.808f,
    0.48f, 0.48f, 0.38f, 0.38f, 0.428f, 0.62f, 0.76f, 0.76f, 0.86f,
    0.86f, 0.62f, 0.76f, 0.76f, 0.86f, 0.86f, 0.62f, 1.0f};

__device__ __forceinline__ int point_index(float px, float py) {
#pragma clang fp contract(off)
    int idx = 0;
    // Reverse iterate + overwrite => lowest-index match wins (== argmax of
    // the boolean "close" vector, matching the reference exactly).
#pragma unroll
    for (int n = 25; n >= 0; --n) {
        float tx = 0.01f + 1.0e-5f * kNX[n];
        float ty = 0.01f + 1.0e-5f * kNY[n];
        bool c = (fabsf(px - kNX[n]) <= tx) && (fabsf(py - kNY[n]) <= ty);
        if (c) idx = n + 1;
    }
    return idx;
}

// ===========================================================================
// Dispatch A: idx pairs -> d_ws (u32 per token: i1 | i2<<8). ~5us.
// ===========================================================================
__global__ __launch_bounds__(THREADS) void idx_kernel(
    const float* __restrict__ x, unsigned* __restrict__ ws, int n_tokens) {
    const float2* x2 = (const float2*)x;
    int stride = gridDim.x * THREADS;
    for (int t = blockIdx.x * THREADS + threadIdx.x; t < n_tokens; t += stride) {
        float2 a = x2[t * 8 + 2];   // x4, x5
        float2 b = x2[t * 8 + 4];   // x8, x9
        unsigned i1 = (unsigned)point_index(a.x, a.y);
        unsigned i2 = (unsigned)point_index(b.x, b.y);
        ws[t] = i1 | (i2 << 8);
    }
}

// ===========================================================================
// Dispatch B: fill-clone writer. Grid-strided single sliding window,
// independent iterations, no LDS, no barriers.
// Output vec4 l: t = l/68, j = l%68. Half h (float2 units, 0..135):
//   h<3: x[2h..]  h<67: e1[2h-6..]  h<69: x[2h-128..]
//   h<133: e2[2h-138..]  else x[2h-256..]      (mapping verified since R6)
// ===========================================================================
__device__ __forceinline__ vfloat4 make_out(const float2* __restrict__ x2,
                                            const float2* __restrict__ e2,
                                            const unsigned* __restrict__ ws,
                                            unsigned l) {
    // exact floor(l/68) for l < 268M: M = ceil(2^32/68) = 63161284, e = 16
    unsigned t = __umulhi(l, 63161284u);
    int j  = (int)(l - t * 68u);
    int tb = (int)t * 8;
    unsigned w = ws[t];
    int i1 = (int)(w & 0xffu) * 64;
    int i2 = (int)(w >> 8)   * 64;
    int h0 = 2 * j, h1 = h0 + 1;
    const float2* p0 = (h0 < 3)   ? x2 + tb + h0
                     : (h0 < 67)  ? e2 + i1 + (h0 - 3)
                     : (h0 < 69)  ? x2 + tb + (h0 - 64)
                     : (h0 < 133) ? e2 + i2 + (h0 - 69)
                     :              x2 + tb + (h0 - 128);
    const float2* p1 = (h1 < 3)   ? x2 + tb + h1
                     : (h1 < 67)  ? e2 + i1 + (h1 - 3)
                     : (h1 < 69)  ? x2 + tb + (h1 - 64)
                     : (h1 < 133) ? e2 + i2 + (h1 - 69)
                     :              x2 + tb + (h1 - 128);
    float2 a = *p0, b = *p1;
    vfloat4 v; v.x = a.x; v.y = a.y; v.z = b.x; v.w = b.y;
    return v;
}

__global__ __launch_bounds__(THREADS) void out_kernel(
    const float* __restrict__ x, const float* __restrict__ emb,
    const unsigned* __restrict__ ws, float* __restrict__ out, int n_tokens) {
    const float2* x2 = (const float2*)x;
    const float2* e2 = (const float2*)emb;
    vfloat4* o4 = (vfloat4*)out;

    const unsigned nvec   = (unsigned)n_tokens * 68u;
    const unsigned stride = gridDim.x * THREADS;
    const unsigned gid    = blockIdx.x * THREADS + threadIdx.x;
    // `full` iterations are in-bounds for EVERY gid < stride:
    //   gid + (full-1)*stride < full*stride <= nvec
    const unsigned full = nvec / stride;

    unsigned l = gid;
#pragma unroll 4
    for (unsigned i = 0; i < full; ++i, l += stride)
        o4[l] = make_out(x2, e2, ws, l);          // plain store (no-RFO, R10)
    if (l < nvec)
        o4[l] = make_out(x2, e2, ws, l);
}

// ===========================================================================
// Fallback (ws too small): R8 kernel verbatim (known-correct, ~115us).
// ===========================================================================
__global__ __launch_bounds__(THREADS) void pos_enc_kernel(
    const float* __restrict__ x, const float* __restrict__ emb,
    float* __restrict__ out, int n_tokens) {
    __shared__ float xs[TOK * 16];
    __shared__ float semb[27 * 128];
    __shared__ int   sidx[2 * TOK];

    const int tid  = threadIdx.x;
    const int tok0 = blockIdx.x * TOK;
    const int ntok = min(TOK, n_tokens - tok0);

    for (int i = tid; i < 27 * 32; i += THREADS)
        ((vfloat4*)semb)[i] = ((const vfloat4*)emb)[i];

    if (tid < ntok * 4) {
        vfloat4 v = ((const vfloat4*)x)[(long long)tok0 * 4 + tid];
        ((vfloat4*)xs)[tid] = v;
        int q = tid & 3, t = tid >> 2;
        if (q == 1) sidx[t]       = point_index(v.x, v.y);
        if (q == 2) sidx[TOK + t] = point_index(v.x, v.y);
    }
    __syncthreads();

    const float2* xs2 = (const float2*)xs;
    const float2* se2 = (const float2*)semb;
    const long long out4 = (long long)tok0 * 68;

#define BODY(lv)                                                           \
    {                                                                      \
        const int l_ = (lv);                                               \
        int t  = (int)(((unsigned)l_ * 61681u) >> 22);                     \
        int j  = l_ - t * 68;                                              \
        int i1 = sidx[t];                                                  \
        int i2 = sidx[TOK + t];                                            \
        int tb = t * 8;                                                    \
        int h0 = 2 * j;                                                    \
        const float2* p0 = (h0 < 3)   ? xs2 + tb + h0                      \
                         : (h0 < 67)  ? se2 + i1 * 64 + (h0 - 3)           \
                         : (h0 < 69)  ? xs2 + tb + (h0 - 64)               \
                         : (h0 < 133) ? se2 + i2 * 64 + (h0 - 69)          \
                         :              xs2 + tb + (h0 - 128);             \
        int h1 = h0 + 1;                                                   \
        const float2* p1 = (h1 < 3)   ? xs2 + tb + h1                      \
                         : (h1 < 67)  ? se2 + i1 * 64 + (h1 - 3)           \
                         : (h1 < 69)  ? xs2 + tb + (h1 - 64)               \
                         : (h1 < 133) ? se2 + i2 * 64 + (h1 - 69)          \
                         :              xs2 + tb + (h1 - 128);             \
        float2 a = *p0, b = *p1;                                           \
        vfloat4 v; v.x = a.x; v.y = a.y; v.z = b.x; v.w = b.y;             \
        ((vfloat4*)out)[out4 + l_] = v;                                    \
    }

    if (ntok == TOK) {
#pragma unroll 4
        for (int k = 0; k < 17; ++k) BODY(tid + (k << 8));
    } else {
        const int nvec = ntok * 68;
        for (int l = tid; l < nvec; l += THREADS) BODY(l);
    }
#undef BODY
}

extern "C" void kernel_launch(void* const* d_in, const int* in_sizes, int n_in,
                              void* d_out, int out_size, void* d_ws, size_t ws_size,
                              hipStream_t stream) {
    const float* x   = (const float*)d_in[0];   // [B, T, 16] f32
    const float* emb = (const float*)d_in[1];   // [100, 128] f32
    float* out = (float*)d_out;                 // [B, T, 272] f32

    int n_tokens = in_sizes[0] / 16;            // 262144

    if (d_ws && ws_size >= (size_t)n_tokens * sizeof(unsigned)) {
        unsigned* ws = (unsigned*)d_ws;
        idx_kernel<<<1024, THREADS, 0, stream>>>(x, ws, n_tokens);
        // 2048 blocks * 256 thr = 524288 lanes; 17825792 vec4 -> 34 full
        // iterations, zero tail at the standard shape.
        out_kernel<<<2048, THREADS, 0, stream>>>(x, emb, ws, out, n_tokens);
    } else {
        int nblocks = (n_tokens + TOK - 1) / TOK;
        pos_enc_kernel<<<nblocks, THREADS, 0, stream>>>(x, emb, out, n_tokens);
    }
}

// Round 9
// 304.641 us; speedup vs baseline: 2.3723x; 1.0039x over previous
//
#include <hip/hip_runtime.h>

// ---------------------------------------------------------------------------
// PositionEncoder: per token (B*T = 262144), output 272 f32:
//   x[0:6] | emb[idx1] (128) | x[6:10] | emb[idx2] (128) | x[10:16]
// idx from matching (x[4],x[5]) / (x[8],x[9]) vs 26 nodes,
// close iff |p - node| <= 0.01 + 1e-5*|node| per dim; idx = first match + 1.
//
// FINAL (R13 = R8 restored). Evidence ledger, 8 controlled experiments:
//   dur_us = ~185us harness poison fill + ~35us fixed dispatch overhead +
//   ~115-120us kernel (serial composition proven by R10 sleep probe).
//   Kernel traffic is verified minimal (R10 direct read: WRITE=278.5MB =
//   output exactly, FETCH=8.3MB, no write-allocate/RFO). All structural
//   levers A/B-tested NULL within +-8us noise:
//     store flavor (nt/plain R6/R8), store depth (R11 17-deep bursts),
//     occupancy (R0 4blk vs R6 8blk/CU), barriers (3/1/0), LDS out-tile vs
//     direct vs register-template (R2/R6/R7), address pattern (per-block
//     streams vs fill-clone global sliding window, R12).
//   Store issue + L2 write path cheap (R9: full duplicate pass +27us).
//   Every in-kernel resource models at <10% utilization; remaining gap vs
//   the 47us pure-write floor is not addressable at HIP source level
//   (R10 sleep-cycle arithmetic suggests reduced shader clock during this
//   low-ALU kernel class). This artifact: simplest, best-tied variant.
// ---------------------------------------------------------------------------

#define TOK 64          // tokens per block
#define THREADS 256

typedef float vfloat4 __attribute__((ext_vector_type(4)));  // native vector

constexpr float kNX[26] = {
    0.5454545454545454f, 0.6022727272727273f, 0.5454545454545454f,
    0.6022727272727273f, 0.4772727272727273f, 0.42045454545454547f,
    0.42045454545454547f, 0.4772727272727273f, 0.32954545454545453f,
    0.42045454545454547f, 0.4772727272727273f, 0.4772727272727273f,
    0.42045454545454547f, 0.32954545454545453f, 0.5727272727272728f,
    0.7613636363636364f, 0.8181818181818182f, 0.8181818181818182f,
    0.7613636363636364f, 0.7909090909090909f, 0.9431818181818182f,
    1.0f, 1.0f, 0.9431818181818182f, 0.9727272727272728f, 0.9727272727272728f};
constexpr float kNY[26] = {
    0.76f, 0.76f, 0.86f, 0.86f, 0.76f, 0.76f, 0.86f, 0.86f, 0.808f,
    0.48f, 0.48f, 0.38f, 0.38f, 0.428f, 0.62f, 0.76f, 0.76f, 0.86f,
    0.86f, 0.62f, 0.76f, 0.76f, 0.86f, 0.86f, 0.62f, 1.0f};

__device__ __forceinline__ int point_index(float px, float py) {
#pragma clang fp contract(off)
    int idx = 0;
    // Reverse iterate + overwrite => lowest-index match wins (== argmax of
    // the boolean "close" vector, matching the reference exactly).
#pragma unroll
    for (int n = 25; n >= 0; --n) {
        float tx = 0.01f + 1.0e-5f * kNX[n];   // compile-time folded
        float ty = 0.01f + 1.0e-5f * kNY[n];
        bool c = (fabsf(px - kNX[n]) <= tx) && (fabsf(py - kNY[n]) <= ty);
        if (c) idx = n + 1;
    }
    return idx;
}

__global__ __launch_bounds__(THREADS) void pos_enc_kernel(
    const float* __restrict__ x, const float* __restrict__ emb,
    float* __restrict__ out, int n_tokens) {
    __shared__ float xs[TOK * 16];      // 4 KB   staged x tile
    __shared__ float semb[27 * 128];    // 13.5 KB emb rows 0..26 (reachable set)
    __shared__ int   sidx[2 * TOK];     // 0.5 KB node indices

    const int tid  = threadIdx.x;
    const int tok0 = blockIdx.x * TOK;
    const int ntok = min(TOK, n_tokens - tok0);

    // ---- stage emb rows 0..26: 864 float4, coalesced, L2-hot after block 0
    for (int i = tid; i < 27 * 32; i += THREADS)
        ((vfloat4*)semb)[i] = ((const vfloat4*)emb)[i];

    // ---- stage x tile (1 float4/thread) + node indices from the staging reg
    if (tid < ntok * 4) {
        vfloat4 v = ((const vfloat4*)x)[(long long)tok0 * 4 + tid];
        ((vfloat4*)xs)[tid] = v;
        int q = tid & 3, t = tid >> 2;
        if (q == 1) sidx[t]       = point_index(v.x, v.y);
        if (q == 2) sidx[TOK + t] = point_index(v.x, v.y);
    }
    __syncthreads();   // the only barrier

    // ---- direct store: flat l -> (t = l/68, j = l%68) float4 of the row.
    // All row-segment boundaries (floats 6,134,138,266) are even, so each
    // 16B output vec4 is two float2 halves, each from exactly one source.
    // Half h (float2 units, 0..135):
    //   h<3: x[2h..]  h<67: e1[2h-6..]  h<69: x[2h-128..]
    //   h<133: e2[2h-138..]  else x[2h-256..]      (verified: absmax 0)
    const float2* xs2 = (const float2*)xs;
    const float2* se2 = (const float2*)semb;
    const long long out4 = (long long)tok0 * 68;

    // exact for l < ~1M: floor(l*61681 / 2^22) == floor(l/68)
#define BODY(lv)                                                           \
    {                                                                      \
        const int l_ = (lv);                                               \
        int t  = (int)(((unsigned)l_ * 61681u) >> 22);                     \
        int j  = l_ - t * 68;                                              \
        int i1 = sidx[t];                                                  \
        int i2 = sidx[TOK + t];                                            \
        int tb = t * 8;                                                    \
        int h0 = 2 * j;                                                    \
        const float2* p0 = (h0 < 3)   ? xs2 + tb + h0                      \
                         : (h0 < 67)  ? se2 + i1 * 64 + (h0 - 3)           \
                         : (h0 < 69)  ? xs2 + tb + (h0 - 64)               \
                         : (h0 < 133) ? se2 + i2 * 64 + (h0 - 69)          \
                         :              xs2 + tb + (h0 - 128);             \
        int h1 = h0 + 1;                                                   \
        const float2* p1 = (h1 < 3)   ? xs2 + tb + h1                      \
                         : (h1 < 67)  ? se2 + i1 * 64 + (h1 - 3)           \
                         : (h1 < 69)  ? xs2 + tb + (h1 - 64)               \
                         : (h1 < 133) ? se2 + i2 * 64 + (h1 - 69)          \
                         :              xs2 + tb + (h1 - 128);             \
        float2 a = *p0, b = *p1;                                           \
        vfloat4 v; v.x = a.x; v.y = a.y; v.z = b.x; v.w = b.y;             \
        ((vfloat4*)out)[out4 + l_] = v;   /* plain store: no-RFO (R10) */  \
    }

    if (ntok == TOK) {
        // full block: every thread does exactly 17 vec4 (64*68/256)
#pragma unroll 4
        for (int k = 0; k < 17; ++k) BODY(tid + (k << 8));
    } else {
        const int nvec = ntok * 68;
        for (int l = tid; l < nvec; l += THREADS) BODY(l);
    }
#undef BODY
}

extern "C" void kernel_launch(void* const* d_in, const int* in_sizes, int n_in,
                              void* d_out, int out_size, void* d_ws, size_t ws_size,
                              hipStream_t stream) {
    const float* x   = (const float*)d_in[0];   // [B, T, 16] f32
    const float* emb = (const float*)d_in[1];   // [100, 128] f32
    float* out = (float*)d_out;                 // [B, T, 272] f32

    int n_tokens = in_sizes[0] / 16;            // 262144
    int nblocks  = (n_tokens + TOK - 1) / TOK;  // 4096

    pos_enc_kernel<<<nblocks, THREADS, 0, stream>>>(x, emb, out, n_tokens);
}